// Round 5
// baseline (489.152 us; speedup 1.0000x reference)
//
#include <hip/hip_runtime.h>
#include <hip/hip_bf16.h>

#define D 128
#define NG 128

typedef __attribute__((ext_vector_type(8))) short bf16x8;
typedef __attribute__((ext_vector_type(4))) float f32x4;

__device__ inline unsigned short f2bf(float f) {
  union { float f; unsigned u; } c; c.f = f;
  unsigned u = c.u;
  return (unsigned short)((u + 0x7FFFu + ((u >> 16) & 1u)) >> 16);  // RNE
}
__device__ inline float bf2f(unsigned short b) {
  union { unsigned u; float f; } c; c.u = ((unsigned)b) << 16;
  return c.f;
}

// Transpose + bf16-convert weights: Wt[l][n][k] = bf16(W[l][k][n]).
// Also zeroes deg[] and g[] (folded to save launches).
__global__ void prep_w(const float* __restrict__ W1, const float* __restrict__ W2,
                       unsigned short* __restrict__ Wt1, unsigned short* __restrict__ Wt2,
                       int* __restrict__ deg, int N, float* __restrict__ g) {
  int t = blockIdx.x * 256 + threadIdx.x;
  if (t < N) deg[t] = 0;
  if (t < NG * D) g[t] = 0.f;
  if (t >= 3 * 128 * 128) return;
  int l = t >> 14, k = (t >> 7) & 127, n = t & 127;
  int o = (l << 14) + (n << 7) + k;
  Wt1[o] = f2bf(W1[t]);
  Wt2[o] = f2bf(W2[t]);
}

// x (row-major f32) -> bf16 column panels: xp[p][n][0..16) = x[n][16p..16p+16)
__global__ void prep_xp(const float* __restrict__ x, unsigned short* __restrict__ xp, int N) {
  int t = blockIdx.x * 256 + threadIdx.x;   // t = n*8 + p
  if (t >= N * 8) return;
  int n = t >> 3, p = t & 7;
  const float* src = x + (size_t)n * D + p * 16;
  float4 v0 = *(const float4*)(src);
  float4 v1 = *(const float4*)(src + 4);
  float4 v2 = *(const float4*)(src + 8);
  float4 v3 = *(const float4*)(src + 12);
  bf16x8 o0, o1;
  o0[0] = (short)f2bf(v0.x); o0[1] = (short)f2bf(v0.y);
  o0[2] = (short)f2bf(v0.z); o0[3] = (short)f2bf(v0.w);
  o0[4] = (short)f2bf(v1.x); o0[5] = (short)f2bf(v1.y);
  o0[6] = (short)f2bf(v1.z); o0[7] = (short)f2bf(v1.w);
  o1[0] = (short)f2bf(v2.x); o1[1] = (short)f2bf(v2.y);
  o1[2] = (short)f2bf(v2.z); o1[3] = (short)f2bf(v2.w);
  o1[4] = (short)f2bf(v3.x); o1[5] = (short)f2bf(v3.y);
  o1[6] = (short)f2bf(v3.z); o1[7] = (short)f2bf(v3.w);
  unsigned short* dstp = xp + (size_t)p * N * 16 + (size_t)n * 16;
  *(bf16x8*)(dstp)     = o0;
  *(bf16x8*)(dstp + 8) = o1;
}

// ---------------- CSR build ------------------------------------------------

__global__ void hist_deg(const int* __restrict__ dst, int* __restrict__ deg, int E) {
  int e = blockIdx.x * 256 + threadIdx.x;
  if (e < E) atomicAdd(deg + dst[e], 1);
}

__global__ __launch_bounds__(256) void scan1(const int* __restrict__ deg,
    int* __restrict__ rowptr, int* __restrict__ bsum, int n) {
  __shared__ int sh[256];
  int tid = threadIdx.x;
  int idx = blockIdx.x * 1024 + tid * 4;
  int v[4], tsum = 0;
#pragma unroll
  for (int j = 0; j < 4; ++j) { v[j] = (idx + j < n) ? deg[idx + j] : 0; tsum += v[j]; }
  sh[tid] = tsum;
  __syncthreads();
  for (int off = 1; off < 256; off <<= 1) {
    int x = (tid >= off) ? sh[tid - off] : 0;
    __syncthreads();
    sh[tid] += x;
    __syncthreads();
  }
  if (tid == 255) bsum[blockIdx.x] = sh[255];
  int run = sh[tid] - tsum;
#pragma unroll
  for (int j = 0; j < 4; ++j) { if (idx + j < n) rowptr[idx + j] = run; run += v[j]; }
}

// single 128-thread block scan of per-block sums (nb <= 128)
__global__ __launch_bounds__(128) void scan2(int* __restrict__ bsum, int nb) {
  __shared__ int sh[128];
  int tid = threadIdx.x;
  int v = (tid < nb) ? bsum[tid] : 0;
  sh[tid] = v;
  __syncthreads();
  for (int off = 1; off < 128; off <<= 1) {
    int x = (tid >= off) ? sh[tid - off] : 0;
    __syncthreads();
    sh[tid] += x;
    __syncthreads();
  }
  if (tid < nb) bsum[tid] = sh[tid] - v;
}

__global__ void scan3(int* __restrict__ rowptr, int* __restrict__ pos,
                      const int* __restrict__ bsum, int n, int E) {
  int t = blockIdx.x * 256 + threadIdx.x;
  if (t < n) {
    int v = rowptr[t] + bsum[t >> 10];
    rowptr[t] = v;
    pos[t] = v;
  }
  if (t == 0) rowptr[n] = E;
}

__global__ void edge_scatter(const int* __restrict__ src, const int* __restrict__ dst,
                             int* __restrict__ pos, int* __restrict__ csr_src, int E) {
  int e = blockIdx.x * 256 + threadIdx.x;
  if (e >= E) return;
  int idx = atomicAdd(pos + dst[e], 1);
  csr_src[idx] = src[e];
}

// ---------------- XCD-panel gather -----------------------------------------
// z is stored as 8 column panels of N x 16 bf16 (3.2 MB each, < 4 MB L2/XCD).
// Block b handles panel (b & 7) and 32 nodes; round-robin dispatch pins panel
// p to XCD p, so after first touch every neighbor read is an L2 hit. Per
// node, 8 lanes each own one (pseudo-)edge -- i==0 is the self row -- with a
// 32B contiguous panel read; partials are combined by a 3-round shfl_xor
// butterfly. csr_src reads and agg writes are nontemporal so streaming
// traffic does not evict the panel from L2.

__global__ __launch_bounds__(256) void gather_panel(const unsigned short* __restrict__ zp,
    const int* __restrict__ rowptr, const int* __restrict__ csr_src,
    unsigned short* __restrict__ agg, int N) {
  int tid = threadIdx.x;
  int p = blockIdx.x & 7;
  int grp = tid >> 3;            // 0..31
  int li  = tid & 7;
  int n = (blockIdx.x >> 3) * 32 + grp;
  if (n >= N) return;
  const unsigned short* panel = zp + (size_t)p * N * 16;

  int e0 = rowptr[n], e1 = rowptr[n + 1];
  int cnt = e1 - e0 + 1;         // +1: pseudo-edge 0 = self row

  float acc[16];
#pragma unroll
  for (int j = 0; j < 16; ++j) acc[j] = 0.f;

  for (int i = li; i < cnt; i += 8) {
    int s = (i == 0) ? n : __builtin_nontemporal_load(csr_src + e0 + i - 1);
    const unsigned short* q = panel + (size_t)s * 16;
    bf16x8 v0 = *(const bf16x8*)(q);
    bf16x8 v1 = *(const bf16x8*)(q + 8);
#pragma unroll
    for (int j = 0; j < 8; ++j) {
      acc[j]     += bf2f((unsigned short)v0[j]);
      acc[j + 8] += bf2f((unsigned short)v1[j]);
    }
  }

  // butterfly reduce across the 8 lanes of the group
#pragma unroll
  for (int off = 1; off < 8; off <<= 1) {
#pragma unroll
    for (int j = 0; j < 16; ++j)
      acc[j] += __shfl_xor(acc[j], off, 64);
  }

  if (li < 2) {
    bf16x8 o;
#pragma unroll
    for (int j = 0; j < 8; ++j) o[j] = (short)f2bf(acc[li * 8 + j]);
    __builtin_nontemporal_store(o, (bf16x8*)(agg + (size_t)n * D + p * 16 + li * 8));
  }
}

// ---------------- fused per-layer MLP: z = ReLU(ReLU(A@W1+b1)@W2+b2) -------
// 128 rows/block, 32 rows/warp, 2-row fragments; all B-fragments + biases
// hoisted to registers. Non-LAST output is written in panel layout for the
// next gather.

template<bool LAST>
__global__ __launch_bounds__(256) void gemm_fused(const unsigned short* __restrict__ A,
    const unsigned short* __restrict__ Wt1, const float* __restrict__ b1v,
    const unsigned short* __restrict__ Wt2, const float* __restrict__ b2v,
    unsigned short* __restrict__ Zb, float* __restrict__ Zf, int M) {
  __shared__ unsigned short hs[4][32][136];
  int lane = threadIdx.x & 63;
  int wid  = threadIdx.x >> 6;
  int row_base = blockIdx.x * 128 + wid * 32;
  int c16 = lane & 15;
  int kq  = lane >> 4;
  int koff = kq * 8;

  bf16x8 a[2][4];
#pragma unroll
  for (int fr = 0; fr < 2; ++fr) {
    int row = row_base + fr * 16 + c16;
    row = row < M ? row : M - 1;
#pragma unroll
    for (int kk = 0; kk < 4; ++kk)
      a[fr][kk] = *(const bf16x8*)(A + (size_t)row * D + kk * 32 + koff);
  }

  // hoist all GEMM1 B-fragments + biases
  bf16x8 bf[8][4];
  float  bb[8];
#pragma unroll
  for (int fc = 0; fc < 8; ++fc) {
    bb[fc] = b1v[fc * 16 + c16];
#pragma unroll
    for (int kk = 0; kk < 4; ++kk)
      bf[fc][kk] = *(const bf16x8*)(Wt1 + (size_t)(fc * 16 + c16) * D + kk * 32 + koff);
  }

  // GEMM1 -> LDS
#pragma unroll
  for (int fc = 0; fc < 8; ++fc) {
    f32x4 acc0 = {0.f, 0.f, 0.f, 0.f};
    f32x4 acc1 = {0.f, 0.f, 0.f, 0.f};
    int col = fc * 16 + c16;
#pragma unroll
    for (int kk = 0; kk < 4; ++kk) {
      acc0 = __builtin_amdgcn_mfma_f32_16x16x32_bf16(a[0][kk], bf[fc][kk], acc0, 0, 0, 0);
      acc1 = __builtin_amdgcn_mfma_f32_16x16x32_bf16(a[1][kk], bf[fc][kk], acc1, 0, 0, 0);
    }
#pragma unroll
    for (int r = 0; r < 4; ++r) {
      int rl = kq * 4 + r;
      hs[wid][rl][col]      = f2bf(fmaxf(acc0[r] + bb[fc], 0.f));
      hs[wid][rl + 16][col] = f2bf(fmaxf(acc1[r] + bb[fc], 0.f));
    }
  }
  __syncthreads();

  bf16x8 a2[2][4];
#pragma unroll
  for (int fr = 0; fr < 2; ++fr)
#pragma unroll
    for (int kk = 0; kk < 4; ++kk)
      a2[fr][kk] = *(const bf16x8*)&hs[wid][fr * 16 + c16][kk * 32 + koff];

  // reload bf/bb with GEMM2 weights
#pragma unroll
  for (int fc = 0; fc < 8; ++fc) {
    bb[fc] = b2v[fc * 16 + c16];
#pragma unroll
    for (int kk = 0; kk < 4; ++kk)
      bf[fc][kk] = *(const bf16x8*)(Wt2 + (size_t)(fc * 16 + c16) * D + kk * 32 + koff);
  }

  // GEMM2 -> global
#pragma unroll
  for (int fc = 0; fc < 8; ++fc) {
    f32x4 acc0 = {0.f, 0.f, 0.f, 0.f};
    f32x4 acc1 = {0.f, 0.f, 0.f, 0.f};
    int col = fc * 16 + c16;
#pragma unroll
    for (int kk = 0; kk < 4; ++kk) {
      acc0 = __builtin_amdgcn_mfma_f32_16x16x32_bf16(a2[0][kk], bf[fc][kk], acc0, 0, 0, 0);
      acc1 = __builtin_amdgcn_mfma_f32_16x16x32_bf16(a2[1][kk], bf[fc][kk], acc1, 0, 0, 0);
    }
    int pp  = col >> 4;
    int off = col & 15;
#pragma unroll
    for (int r = 0; r < 4; ++r) {
      int row0 = row_base + kq * 4 + r;
      float v0 = fmaxf(acc0[r] + bb[fc], 0.f);
      if (row0 < M) {
        if constexpr (LAST) Zf[(size_t)row0 * D + col] = v0;
        else                Zb[(size_t)pp * M * 16 + (size_t)row0 * 16 + off] = f2bf(v0);
      }
      int row1 = row0 + 16;
      float v1 = fmaxf(acc1[r] + bb[fc], 0.f);
      if (row1 < M) {
        if constexpr (LAST) Zf[(size_t)row1 * D + col] = v1;
        else                Zb[(size_t)pp * M * 16 + (size_t)row1 * 16 + off] = f2bf(v1);
      }
    }
  }
}

// ---------------- pooling: sorted batch -> bounds + streaming mean ---------

__global__ __launch_bounds__(128) void pool_bounds(const int* __restrict__ batch,
                                                   int* __restrict__ start, int N) {
  int g = threadIdx.x;   // one block of 128
  int lo = 0, hi = N;
  while (lo < hi) {
    int mid = (lo + hi) >> 1;
    if (batch[mid] < g) lo = mid + 1; else hi = mid;
  }
  start[g] = lo;
  if (g == 0) start[NG] = N;
}

#define PCHUNKS 8
__global__ __launch_bounds__(128) void pool_mean(const float* __restrict__ z,
    const int* __restrict__ start, float* __restrict__ g) {
  int gid   = blockIdx.x >> 3;
  int chunk = blockIdx.x & (PCHUNKS - 1);
  int col = threadIdx.x;
  int s = start[gid], epos = start[gid + 1];
  int len = epos - s;
  if (len <= 0) return;
  int per = (len + PCHUNKS - 1) / PCHUNKS;
  int r0 = s + chunk * per;
  int r1 = min(r0 + per, epos);
  if (r0 >= r1) return;
  float a0 = 0.f, a1 = 0.f, a2 = 0.f, a3 = 0.f;
  int i = r0;
  for (; i + 4 <= r1; i += 4) {
    a0 += z[(size_t)(i + 0) * D + col];
    a1 += z[(size_t)(i + 1) * D + col];
    a2 += z[(size_t)(i + 2) * D + col];
    a3 += z[(size_t)(i + 3) * D + col];
  }
  for (; i < r1; ++i) a0 += z[(size_t)i * D + col];
  atomicAdd(g + (size_t)gid * D + col, (a0 + a1) + (a2 + a3));
}

__global__ void pool_div(float* __restrict__ g, const int* __restrict__ start) {
  int t = blockIdx.x * 256 + threadIdx.x;
  if (t >= NG * D) return;
  int gid = t >> 7;
  int cnt = start[gid + 1] - start[gid];
  g[t] = g[t] / fmaxf((float)cnt, 1.f);
}

extern "C" void kernel_launch(void* const* d_in, const int* in_sizes, int n_in,
                              void* d_out, int out_size, void* d_ws, size_t ws_size,
                              hipStream_t stream) {
  const float* x     = (const float*)d_in[0];
  const int*   ei    = (const int*)d_in[1];
  const int*   batch = (const int*)d_in[2];
  const float* W1    = (const float*)d_in[3];
  const float* b1    = (const float*)d_in[4];
  const float* W2    = (const float*)d_in[5];
  const float* b2    = (const float*)d_in[6];

  const int N = in_sizes[0] / D;       // 100000
  const int E = in_sizes[1] / 2;       // 640000
  const int* src = ei;
  const int* dst = ei + E;

  float* zout = (float*)d_out;
  float* g    = zout + (size_t)N * D;

  // workspace layout
  char* w = (char*)d_ws;
  unsigned short* agg     = (unsigned short*)w;    w += (size_t)N * D * 2;
  unsigned short* zp      = (unsigned short*)w;    w += (size_t)N * D * 2;  // panel z
  unsigned short* xp      = (unsigned short*)w;    w += (size_t)N * D * 2;  // panel x
  unsigned short* Wt1     = (unsigned short*)w;    w += 3 * 16384 * 2;
  unsigned short* Wt2     = (unsigned short*)w;    w += 3 * 16384 * 2;
  int*            start   = (int*)w;               w += (NG + 4) * 4;
  int*            deg     = (int*)w;               w += (size_t)N * 4;
  int*            rowptr  = (int*)w;               w += (size_t)(N + 4) * 4;
  int*            pos     = (int*)w;               w += (size_t)N * 4;
  int*            bsum    = (int*)w;               w += 128 * 4;
  int*            csr_src = (int*)w;               w += (size_t)E * 4;

  const int nb = (N + 1023) / 1024;   // 98 <= 128

  // weight prep + deg/g zero (folded); x -> bf16 panels
  int prep_threads = (3 * 128 * 128 > N) ? 3 * 128 * 128 : N;
  prep_w<<<(prep_threads + 255) / 256, 256, 0, stream>>>(W1, W2, Wt1, Wt2, deg, N, g);
  prep_xp<<<(N * 8 + 255) / 256, 256, 0, stream>>>(x, xp, N);

  // graph boundaries (only needs batch; run early)
  pool_bounds<<<1, 128, 0, stream>>>(batch, start, N);

  // CSR build
  hist_deg<<<(E + 255) / 256, 256, 0, stream>>>(dst, deg, E);
  scan1<<<nb, 256, 0, stream>>>(deg, rowptr, bsum, N);
  scan2<<<1, 128, 0, stream>>>(bsum, nb);
  scan3<<<(N + 255) / 256, 256, 0, stream>>>(rowptr, pos, bsum, N, E);
  edge_scatter<<<(E + 255) / 256, 256, 0, stream>>>(src, dst, pos, csr_src, E);

  const int gather_blocks = 8 * ((N + 31) / 32);   // 8 panels x node chunks
  const int gemm_blocks   = (N + 127) / 128;       // 782

  // layer 0
  gather_panel<<<gather_blocks, 256, 0, stream>>>(xp, rowptr, csr_src, agg, N);
  gemm_fused<false><<<gemm_blocks, 256, 0, stream>>>(agg, Wt1, b1, Wt2, b2, zp, zout, N);
  // layer 1
  gather_panel<<<gather_blocks, 256, 0, stream>>>(zp, rowptr, csr_src, agg, N);
  gemm_fused<false><<<gemm_blocks, 256, 0, stream>>>(agg, Wt1 + 16384, b1 + 128,
                                                     Wt2 + 16384, b2 + 128, zp, zout, N);
  // layer 2 (writes f32 zout)
  gather_panel<<<gather_blocks, 256, 0, stream>>>(zp, rowptr, csr_src, agg, N);
  gemm_fused<true><<<gemm_blocks, 256, 0, stream>>>(agg, Wt1 + 32768, b1 + 256,
                                                    Wt2 + 32768, b2 + 256, zp, zout, N);

  pool_mean<<<NG * PCHUNKS, 128, 0, stream>>>(zout, start, g);
  pool_div<<<(NG * D + 255) / 256, 256, 0, stream>>>(g, start);
}

// Round 6
// 426.522 us; speedup vs baseline: 1.1468x; 1.1468x over previous
//
#include <hip/hip_runtime.h>
#include <hip/hip_bf16.h>

#define D 128
#define NG 128

typedef __attribute__((ext_vector_type(8))) short bf16x8;
typedef __attribute__((ext_vector_type(4))) float f32x4;

__device__ inline unsigned short f2bf(float f) {
  union { float f; unsigned u; } c; c.f = f;
  unsigned u = c.u;
  return (unsigned short)((u + 0x7FFFu + ((u >> 16) & 1u)) >> 16);  // RNE
}
__device__ inline float bf2f(unsigned short b) {
  union { unsigned u; float f; } c; c.u = ((unsigned)b) << 16;
  return c.f;
}

// Transpose + bf16-convert weights: Wt[l][n][k] = bf16(W[l][k][n]).
// Also zeroes deg[] and g[] (folded to save launches).
__global__ void prep_w(const float* __restrict__ W1, const float* __restrict__ W2,
                       unsigned short* __restrict__ Wt1, unsigned short* __restrict__ Wt2,
                       int* __restrict__ deg, int N, float* __restrict__ g) {
  int t = blockIdx.x * 256 + threadIdx.x;
  if (t < N) deg[t] = 0;
  if (t < NG * D) g[t] = 0.f;
  if (t >= 3 * 128 * 128) return;
  int l = t >> 14, k = (t >> 7) & 127, n = t & 127;
  int o = (l << 14) + (n << 7) + k;
  Wt1[o] = f2bf(W1[t]);
  Wt2[o] = f2bf(W2[t]);
}

// x (row-major f32) -> bf16 column panels: xp[p][n][0..16) = x[n][16p..16p+16)
__global__ void prep_xp(const float* __restrict__ x, unsigned short* __restrict__ xp, int N) {
  int t = blockIdx.x * 256 + threadIdx.x;   // t = n*8 + p
  if (t >= N * 8) return;
  int n = t >> 3, p = t & 7;
  const float* src = x + (size_t)n * D + p * 16;
  float4 v0 = *(const float4*)(src);
  float4 v1 = *(const float4*)(src + 4);
  float4 v2 = *(const float4*)(src + 8);
  float4 v3 = *(const float4*)(src + 12);
  bf16x8 o0, o1;
  o0[0] = (short)f2bf(v0.x); o0[1] = (short)f2bf(v0.y);
  o0[2] = (short)f2bf(v0.z); o0[3] = (short)f2bf(v0.w);
  o0[4] = (short)f2bf(v1.x); o0[5] = (short)f2bf(v1.y);
  o0[6] = (short)f2bf(v1.z); o0[7] = (short)f2bf(v1.w);
  o1[0] = (short)f2bf(v2.x); o1[1] = (short)f2bf(v2.y);
  o1[2] = (short)f2bf(v2.z); o1[3] = (short)f2bf(v2.w);
  o1[4] = (short)f2bf(v3.x); o1[5] = (short)f2bf(v3.y);
  o1[6] = (short)f2bf(v3.z); o1[7] = (short)f2bf(v3.w);
  unsigned short* dstp = xp + (size_t)p * N * 16 + (size_t)n * 16;
  *(bf16x8*)(dstp)     = o0;
  *(bf16x8*)(dstp + 8) = o1;
}

// ---------------- CSR build ------------------------------------------------

__global__ void hist_deg(const int* __restrict__ dst, int* __restrict__ deg, int E) {
  int e = blockIdx.x * 256 + threadIdx.x;
  if (e < E) atomicAdd(deg + dst[e], 1);
}

__global__ __launch_bounds__(256) void scan1(const int* __restrict__ deg,
    int* __restrict__ rowptr, int* __restrict__ bsum, int n) {
  __shared__ int sh[256];
  int tid = threadIdx.x;
  int idx = blockIdx.x * 1024 + tid * 4;
  int v[4], tsum = 0;
#pragma unroll
  for (int j = 0; j < 4; ++j) { v[j] = (idx + j < n) ? deg[idx + j] : 0; tsum += v[j]; }
  sh[tid] = tsum;
  __syncthreads();
  for (int off = 1; off < 256; off <<= 1) {
    int x = (tid >= off) ? sh[tid - off] : 0;
    __syncthreads();
    sh[tid] += x;
    __syncthreads();
  }
  if (tid == 255) bsum[blockIdx.x] = sh[255];
  int run = sh[tid] - tsum;
#pragma unroll
  for (int j = 0; j < 4; ++j) { if (idx + j < n) rowptr[idx + j] = run; run += v[j]; }
}

// single 128-thread block scan of per-block sums (nb <= 128)
__global__ __launch_bounds__(128) void scan2(int* __restrict__ bsum, int nb) {
  __shared__ int sh[128];
  int tid = threadIdx.x;
  int v = (tid < nb) ? bsum[tid] : 0;
  sh[tid] = v;
  __syncthreads();
  for (int off = 1; off < 128; off <<= 1) {
    int x = (tid >= off) ? sh[tid - off] : 0;
    __syncthreads();
    sh[tid] += x;
    __syncthreads();
  }
  if (tid < nb) bsum[tid] = sh[tid] - v;
}

__global__ void scan3(int* __restrict__ rowptr, int* __restrict__ pos,
                      const int* __restrict__ bsum, int n, int E) {
  int t = blockIdx.x * 256 + threadIdx.x;
  if (t < n) {
    int v = rowptr[t] + bsum[t >> 10];
    rowptr[t] = v;
    pos[t] = v;
  }
  if (t == 0) rowptr[n] = E;
}

__global__ void edge_scatter(const int* __restrict__ src, const int* __restrict__ dst,
                             int* __restrict__ pos, int* __restrict__ csr_src, int E) {
  int e = blockIdx.x * 256 + threadIdx.x;
  if (e >= E) return;
  int idx = atomicAdd(pos + dst[e], 1);
  csr_src[idx] = src[e];
}

// ---------------- XCD-panel gather, zero-shuffle ---------------------------
// z stored as 8 column panels of N x 16 bf16 (3.2 MB < 4 MB L2/XCD). Block b
// handles panel (b & 7); round-robin dispatch pins panel p to XCD p, so
// neighbor reads are L2 hits (R5 proved it: FETCH 177 -> 28.6 MB). R5's VALU
// bottleneck (75% busy: 96 butterfly ops/node-lane vs ~30 useful) is removed
// by the R4 decomposition at panel width: 2 lanes per node, each owning 8
// cols across ALL the node's edges -- no cross-lane reduce at all. 4-edge
// batches keep 4 independent L2-hit loads in flight per lane.

__global__ __launch_bounds__(256) void gather_panel(const unsigned short* __restrict__ zp,
    const int* __restrict__ rowptr, const int* __restrict__ csr_src,
    unsigned short* __restrict__ agg, int N) {
  int tid = threadIdx.x;
  int p = blockIdx.x & 7;
  int n = (blockIdx.x >> 3) * 128 + (tid >> 1);
  if (n >= N) return;
  int li = tid & 1;            // which 8-col half of the panel row
  const unsigned short* panel = zp + (size_t)p * N * 16 + li * 8;

  float acc[8];
  {
    bf16x8 v = *(const bf16x8*)(panel + (size_t)n * 16);
#pragma unroll
    for (int j = 0; j < 8; ++j) acc[j] = bf2f((unsigned short)v[j]);
  }

  int e  = rowptr[n];
  int e1 = rowptr[n + 1];

  for (; e + 4 <= e1; e += 4) {
    int s0 = __builtin_nontemporal_load(csr_src + e + 0);
    int s1 = __builtin_nontemporal_load(csr_src + e + 1);
    int s2 = __builtin_nontemporal_load(csr_src + e + 2);
    int s3 = __builtin_nontemporal_load(csr_src + e + 3);
    bf16x8 v0 = *(const bf16x8*)(panel + (size_t)s0 * 16);
    bf16x8 v1 = *(const bf16x8*)(panel + (size_t)s1 * 16);
    bf16x8 v2 = *(const bf16x8*)(panel + (size_t)s2 * 16);
    bf16x8 v3 = *(const bf16x8*)(panel + (size_t)s3 * 16);
#pragma unroll
    for (int j = 0; j < 8; ++j) {
      float a = bf2f((unsigned short)v0[j]) + bf2f((unsigned short)v1[j]);
      float b = bf2f((unsigned short)v2[j]) + bf2f((unsigned short)v3[j]);
      acc[j] += a + b;
    }
  }
  if (e + 2 <= e1) {
    int s0 = __builtin_nontemporal_load(csr_src + e + 0);
    int s1 = __builtin_nontemporal_load(csr_src + e + 1);
    bf16x8 v0 = *(const bf16x8*)(panel + (size_t)s0 * 16);
    bf16x8 v1 = *(const bf16x8*)(panel + (size_t)s1 * 16);
#pragma unroll
    for (int j = 0; j < 8; ++j)
      acc[j] += bf2f((unsigned short)v0[j]) + bf2f((unsigned short)v1[j]);
    e += 2;
  }
  if (e < e1) {
    int s0 = __builtin_nontemporal_load(csr_src + e);
    bf16x8 v0 = *(const bf16x8*)(panel + (size_t)s0 * 16);
#pragma unroll
    for (int j = 0; j < 8; ++j)
      acc[j] += bf2f((unsigned short)v0[j]);
  }

  bf16x8 o;
#pragma unroll
  for (int j = 0; j < 8; ++j) o[j] = (short)f2bf(acc[j]);
  __builtin_nontemporal_store(o, (bf16x8*)(agg + (size_t)n * D + p * 16 + li * 8));
}

// ---------------- fused per-layer MLP: z = ReLU(ReLU(A@W1+b1)@W2+b2) -------
// 128 rows/block, 32 rows/warp, 2-row fragments; all B-fragments + biases
// hoisted to registers. Non-LAST output is staged in the warp-private hs LDS
// tile and written to panel layout as bf16x8 (1KB contiguous per wave store
// instruction) -- R5's direct 2B panel stores were 4x32B scatter per instr.

template<bool LAST>
__global__ __launch_bounds__(256) void gemm_fused(const unsigned short* __restrict__ A,
    const unsigned short* __restrict__ Wt1, const float* __restrict__ b1v,
    const unsigned short* __restrict__ Wt2, const float* __restrict__ b2v,
    unsigned short* __restrict__ Zb, float* __restrict__ Zf, int M) {
  __shared__ unsigned short hs[4][32][136];
  int lane = threadIdx.x & 63;
  int wid  = threadIdx.x >> 6;
  int row_base = blockIdx.x * 128 + wid * 32;
  int c16 = lane & 15;
  int kq  = lane >> 4;
  int koff = kq * 8;

  bf16x8 a[2][4];
#pragma unroll
  for (int fr = 0; fr < 2; ++fr) {
    int row = row_base + fr * 16 + c16;
    row = row < M ? row : M - 1;
#pragma unroll
    for (int kk = 0; kk < 4; ++kk)
      a[fr][kk] = *(const bf16x8*)(A + (size_t)row * D + kk * 32 + koff);
  }

  // hoist all GEMM1 B-fragments + biases
  bf16x8 bf[8][4];
  float  bb[8];
#pragma unroll
  for (int fc = 0; fc < 8; ++fc) {
    bb[fc] = b1v[fc * 16 + c16];
#pragma unroll
    for (int kk = 0; kk < 4; ++kk)
      bf[fc][kk] = *(const bf16x8*)(Wt1 + (size_t)(fc * 16 + c16) * D + kk * 32 + koff);
  }

  // GEMM1 -> LDS
#pragma unroll
  for (int fc = 0; fc < 8; ++fc) {
    f32x4 acc0 = {0.f, 0.f, 0.f, 0.f};
    f32x4 acc1 = {0.f, 0.f, 0.f, 0.f};
    int col = fc * 16 + c16;
#pragma unroll
    for (int kk = 0; kk < 4; ++kk) {
      acc0 = __builtin_amdgcn_mfma_f32_16x16x32_bf16(a[0][kk], bf[fc][kk], acc0, 0, 0, 0);
      acc1 = __builtin_amdgcn_mfma_f32_16x16x32_bf16(a[1][kk], bf[fc][kk], acc1, 0, 0, 0);
    }
#pragma unroll
    for (int r = 0; r < 4; ++r) {
      int rl = kq * 4 + r;
      hs[wid][rl][col]      = f2bf(fmaxf(acc0[r] + bb[fc], 0.f));
      hs[wid][rl + 16][col] = f2bf(fmaxf(acc1[r] + bb[fc], 0.f));
    }
  }
  __syncthreads();

  bf16x8 a2[2][4];
#pragma unroll
  for (int fr = 0; fr < 2; ++fr)
#pragma unroll
    for (int kk = 0; kk < 4; ++kk)
      a2[fr][kk] = *(const bf16x8*)&hs[wid][fr * 16 + c16][kk * 32 + koff];

  // reload bf/bb with GEMM2 weights
#pragma unroll
  for (int fc = 0; fc < 8; ++fc) {
    bb[fc] = b2v[fc * 16 + c16];
#pragma unroll
    for (int kk = 0; kk < 4; ++kk)
      bf[fc][kk] = *(const bf16x8*)(Wt2 + (size_t)(fc * 16 + c16) * D + kk * 32 + koff);
  }

  // GEMM2
#pragma unroll
  for (int fc = 0; fc < 8; ++fc) {
    f32x4 acc0 = {0.f, 0.f, 0.f, 0.f};
    f32x4 acc1 = {0.f, 0.f, 0.f, 0.f};
    int col = fc * 16 + c16;
#pragma unroll
    for (int kk = 0; kk < 4; ++kk) {
      acc0 = __builtin_amdgcn_mfma_f32_16x16x32_bf16(a2[0][kk], bf[fc][kk], acc0, 0, 0, 0);
      acc1 = __builtin_amdgcn_mfma_f32_16x16x32_bf16(a2[1][kk], bf[fc][kk], acc1, 0, 0, 0);
    }
#pragma unroll
    for (int r = 0; r < 4; ++r) {
      float v0 = fmaxf(acc0[r] + bb[fc], 0.f);
      float v1 = fmaxf(acc1[r] + bb[fc], 0.f);
      if constexpr (LAST) {
        int row0 = row_base + kq * 4 + r;
        if (row0 < M)      Zf[(size_t)row0 * D + col] = v0;
        int row1 = row0 + 16;
        if (row1 < M)      Zf[(size_t)row1 * D + col] = v1;
      } else {
        // stage in warp-private LDS (overwrites h tile; data-dep safe)
        hs[wid][kq * 4 + r][col]      = f2bf(v0);
        hs[wid][kq * 4 + r + 16][col] = f2bf(v1);
      }
    }
  }

  if constexpr (!LAST) {
    // panel write-out: per pp, wave writes 32 rows x 16 cols = 1KB contiguous
    int rl   = lane >> 1;
    int half = lane & 1;
    int row  = row_base + rl;
#pragma unroll
    for (int pp = 0; pp < 8; ++pp) {
      bf16x8 v = *(const bf16x8*)&hs[wid][rl][pp * 16 + half * 8];
      if (row < M)
        *(bf16x8*)(Zb + (size_t)pp * M * 16 + (size_t)row * 16 + half * 8) = v;
    }
  }
}

// ---------------- pooling: sorted batch -> bounds + streaming mean ---------

__global__ __launch_bounds__(128) void pool_bounds(const int* __restrict__ batch,
                                                   int* __restrict__ start, int N) {
  int g = threadIdx.x;   // one block of 128
  int lo = 0, hi = N;
  while (lo < hi) {
    int mid = (lo + hi) >> 1;
    if (batch[mid] < g) lo = mid + 1; else hi = mid;
  }
  start[g] = lo;
  if (g == 0) start[NG] = N;
}

#define PCHUNKS 8
__global__ __launch_bounds__(128) void pool_mean(const float* __restrict__ z,
    const int* __restrict__ start, float* __restrict__ g) {
  int gid   = blockIdx.x >> 3;
  int chunk = blockIdx.x & (PCHUNKS - 1);
  int col = threadIdx.x;
  int s = start[gid], epos = start[gid + 1];
  int len = epos - s;
  if (len <= 0) return;
  int per = (len + PCHUNKS - 1) / PCHUNKS;
  int r0 = s + chunk * per;
  int r1 = min(r0 + per, epos);
  if (r0 >= r1) return;
  float a0 = 0.f, a1 = 0.f, a2 = 0.f, a3 = 0.f;
  int i = r0;
  for (; i + 4 <= r1; i += 4) {
    a0 += z[(size_t)(i + 0) * D + col];
    a1 += z[(size_t)(i + 1) * D + col];
    a2 += z[(size_t)(i + 2) * D + col];
    a3 += z[(size_t)(i + 3) * D + col];
  }
  for (; i < r1; ++i) a0 += z[(size_t)i * D + col];
  atomicAdd(g + (size_t)gid * D + col, (a0 + a1) + (a2 + a3));
}

__global__ void pool_div(float* __restrict__ g, const int* __restrict__ start) {
  int t = blockIdx.x * 256 + threadIdx.x;
  if (t >= NG * D) return;
  int gid = t >> 7;
  int cnt = start[gid + 1] - start[gid];
  g[t] = g[t] / fmaxf((float)cnt, 1.f);
}

extern "C" void kernel_launch(void* const* d_in, const int* in_sizes, int n_in,
                              void* d_out, int out_size, void* d_ws, size_t ws_size,
                              hipStream_t stream) {
  const float* x     = (const float*)d_in[0];
  const int*   ei    = (const int*)d_in[1];
  const int*   batch = (const int*)d_in[2];
  const float* W1    = (const float*)d_in[3];
  const float* b1    = (const float*)d_in[4];
  const float* W2    = (const float*)d_in[5];
  const float* b2    = (const float*)d_in[6];

  const int N = in_sizes[0] / D;       // 100000
  const int E = in_sizes[1] / 2;       // 640000
  const int* src = ei;
  const int* dst = ei + E;

  float* zout = (float*)d_out;
  float* g    = zout + (size_t)N * D;

  // workspace layout
  char* w = (char*)d_ws;
  unsigned short* agg     = (unsigned short*)w;    w += (size_t)N * D * 2;
  unsigned short* zp      = (unsigned short*)w;    w += (size_t)N * D * 2;  // panel z
  unsigned short* xp      = (unsigned short*)w;    w += (size_t)N * D * 2;  // panel x
  unsigned short* Wt1     = (unsigned short*)w;    w += 3 * 16384 * 2;
  unsigned short* Wt2     = (unsigned short*)w;    w += 3 * 16384 * 2;
  int*            start   = (int*)w;               w += (NG + 4) * 4;
  int*            deg     = (int*)w;               w += (size_t)N * 4;
  int*            rowptr  = (int*)w;               w += (size_t)(N + 4) * 4;
  int*            pos     = (int*)w;               w += (size_t)N * 4;
  int*            bsum    = (int*)w;               w += 128 * 4;
  int*            csr_src = (int*)w;               w += (size_t)E * 4;

  const int nb = (N + 1023) / 1024;   // 98 <= 128

  // weight prep + deg/g zero (folded); x -> bf16 panels
  int prep_threads = (3 * 128 * 128 > N) ? 3 * 128 * 128 : N;
  prep_w<<<(prep_threads + 255) / 256, 256, 0, stream>>>(W1, W2, Wt1, Wt2, deg, N, g);
  prep_xp<<<(N * 8 + 255) / 256, 256, 0, stream>>>(x, xp, N);

  // graph boundaries (only needs batch; run early)
  pool_bounds<<<1, 128, 0, stream>>>(batch, start, N);

  // CSR build
  hist_deg<<<(E + 255) / 256, 256, 0, stream>>>(dst, deg, E);
  scan1<<<nb, 256, 0, stream>>>(deg, rowptr, bsum, N);
  scan2<<<1, 128, 0, stream>>>(bsum, nb);
  scan3<<<(N + 255) / 256, 256, 0, stream>>>(rowptr, pos, bsum, N, E);
  edge_scatter<<<(E + 255) / 256, 256, 0, stream>>>(src, dst, pos, csr_src, E);

  const int gather_blocks = 8 * ((N + 127) / 128);   // 8 panels x node chunks
  const int gemm_blocks   = (N + 127) / 128;         // 782

  // layer 0
  gather_panel<<<gather_blocks, 256, 0, stream>>>(xp, rowptr, csr_src, agg, N);
  gemm_fused<false><<<gemm_blocks, 256, 0, stream>>>(agg, Wt1, b1, Wt2, b2, zp, zout, N);
  // layer 1
  gather_panel<<<gather_blocks, 256, 0, stream>>>(zp, rowptr, csr_src, agg, N);
  gemm_fused<false><<<gemm_blocks, 256, 0, stream>>>(agg, Wt1 + 16384, b1 + 128,
                                                     Wt2 + 16384, b2 + 128, zp, zout, N);
  // layer 2 (writes f32 zout)
  gather_panel<<<gather_blocks, 256, 0, stream>>>(zp, rowptr, csr_src, agg, N);
  gemm_fused<true><<<gemm_blocks, 256, 0, stream>>>(agg, Wt1 + 32768, b1 + 256,
                                                    Wt2 + 32768, b2 + 256, zp, zout, N);

  pool_mean<<<NG * PCHUNKS, 128, 0, stream>>>(zout, start, g);
  pool_div<<<(NG * D + 255) / 256, 256, 0, stream>>>(g, start);
}

// Round 7
// 289.391 us; speedup vs baseline: 1.6903x; 1.4739x over previous
//
#include <hip/hip_runtime.h>
#include <hip/hip_bf16.h>

#define D 128
#define NG 128

typedef __attribute__((ext_vector_type(8))) short bf16x8;
typedef __attribute__((ext_vector_type(4))) float f32x4;

__device__ inline unsigned short f2bf(float f) {
  union { float f; unsigned u; } c; c.f = f;
  unsigned u = c.u;
  return (unsigned short)((u + 0x7FFFu + ((u >> 16) & 1u)) >> 16);  // RNE
}
__device__ inline float bf2f(unsigned short b) {
  union { unsigned u; float f; } c; c.u = ((unsigned)b) << 16;
  return c.f;
}

// Transpose + bf16-convert weights: Wt[l][n][k] = bf16(W[l][k][n]).
// Also zeroes deg[] and g[] (folded to save launches).
__global__ void prep_w(const float* __restrict__ W1, const float* __restrict__ W2,
                       unsigned short* __restrict__ Wt1, unsigned short* __restrict__ Wt2,
                       int* __restrict__ deg, int N, float* __restrict__ g) {
  int t = blockIdx.x * 256 + threadIdx.x;
  if (t < N) deg[t] = 0;
  if (t < NG * D) g[t] = 0.f;
  if (t >= 3 * 128 * 128) return;
  int l = t >> 14, k = (t >> 7) & 127, n = t & 127;
  int o = (l << 14) + (n << 7) + k;
  Wt1[o] = f2bf(W1[t]);
  Wt2[o] = f2bf(W2[t]);
}

// ---------------- CSR build ------------------------------------------------

__global__ void hist_deg(const int* __restrict__ dst, int* __restrict__ deg, int E) {
  int e = blockIdx.x * 256 + threadIdx.x;
  if (e < E) atomicAdd(deg + dst[e], 1);
}

__global__ __launch_bounds__(256) void scan1(const int* __restrict__ deg,
    int* __restrict__ rowptr, int* __restrict__ bsum, int n) {
  __shared__ int sh[256];
  int tid = threadIdx.x;
  int idx = blockIdx.x * 1024 + tid * 4;
  int v[4], tsum = 0;
#pragma unroll
  for (int j = 0; j < 4; ++j) { v[j] = (idx + j < n) ? deg[idx + j] : 0; tsum += v[j]; }
  sh[tid] = tsum;
  __syncthreads();
  for (int off = 1; off < 256; off <<= 1) {
    int x = (tid >= off) ? sh[tid - off] : 0;
    __syncthreads();
    sh[tid] += x;
    __syncthreads();
  }
  if (tid == 255) bsum[blockIdx.x] = sh[255];
  int run = sh[tid] - tsum;
#pragma unroll
  for (int j = 0; j < 4; ++j) { if (idx + j < n) rowptr[idx + j] = run; run += v[j]; }
}

// single 128-thread block scan of per-block sums (nb <= 128)
__global__ __launch_bounds__(128) void scan2(int* __restrict__ bsum, int nb) {
  __shared__ int sh[128];
  int tid = threadIdx.x;
  int v = (tid < nb) ? bsum[tid] : 0;
  sh[tid] = v;
  __syncthreads();
  for (int off = 1; off < 128; off <<= 1) {
    int x = (tid >= off) ? sh[tid - off] : 0;
    __syncthreads();
    sh[tid] += x;
    __syncthreads();
  }
  if (tid < nb) bsum[tid] = sh[tid] - v;
}

__global__ void scan3(int* __restrict__ rowptr, int* __restrict__ pos,
                      const int* __restrict__ bsum, int n, int E) {
  int t = blockIdx.x * 256 + threadIdx.x;
  if (t < n) {
    int v = rowptr[t] + bsum[t >> 10];
    rowptr[t] = v;
    pos[t] = v;
  }
  if (t == 0) rowptr[n] = E;
}

__global__ void edge_scatter(const int* __restrict__ src, const int* __restrict__ dst,
                             int* __restrict__ pos, int* __restrict__ csr_src, int E) {
  int e = blockIdx.x * 256 + threadIdx.x;
  if (e >= E) return;
  int idx = atomicAdd(pos + dst[e], 1);
  csr_src[idx] = src[e];
}

// ---------------- gather aggregation: agg[i] = z[i] + sum neighbors --------
// R4's proven kernel: 8 lanes/node, 8 independent 16B loads in flight, full
// grid. Runs at the memory system's random-granule ceiling (~3.6 TB/s eff,
// 57us) -- panel variants (R5/R6) cut HBM traffic but lost on request count.

template<bool IN_BF16>
__global__ __launch_bounds__(256) void gather_agg(const void* __restrict__ zin,
    const int* __restrict__ rowptr, const int* __restrict__ csr_src,
    unsigned short* __restrict__ agg, int N) {
  int t = blockIdx.x * 256 + threadIdx.x;
  int node = t >> 3;
  if (node >= N) return;
  int c = (t & 7) * 16;    // 16 elements per lane: 32B bf16 / 64B f32
  const float* zf = (const float*)zin;
  const unsigned short* zb = (const unsigned short*)zin;

  float acc[16];

  // self term
  if constexpr (IN_BF16) {
    const unsigned short* p = zb + (size_t)node * D + c;
    bf16x8 v0 = *(const bf16x8*)(p);
    bf16x8 v1 = *(const bf16x8*)(p + 8);
#pragma unroll
    for (int j = 0; j < 8; ++j) {
      acc[j]     = bf2f((unsigned short)v0[j]);
      acc[j + 8] = bf2f((unsigned short)v1[j]);
    }
  } else {
    const float* p = zf + (size_t)node * D + c;
    float4 v0 = *(const float4*)(p);
    float4 v1 = *(const float4*)(p + 4);
    float4 v2 = *(const float4*)(p + 8);
    float4 v3 = *(const float4*)(p + 12);
    acc[0]  = v0.x; acc[1]  = v0.y; acc[2]  = v0.z; acc[3]  = v0.w;
    acc[4]  = v1.x; acc[5]  = v1.y; acc[6]  = v1.z; acc[7]  = v1.w;
    acc[8]  = v2.x; acc[9]  = v2.y; acc[10] = v2.z; acc[11] = v2.w;
    acc[12] = v3.x; acc[13] = v3.y; acc[14] = v3.z; acc[15] = v3.w;
  }

  int e  = rowptr[node];
  int e1 = rowptr[node + 1];

  if constexpr (IN_BF16) {
    for (; e + 4 <= e1; e += 4) {
      int s0 = csr_src[e + 0];
      int s1 = csr_src[e + 1];
      int s2 = csr_src[e + 2];
      int s3 = csr_src[e + 3];
      const unsigned short* p0 = zb + (size_t)s0 * D + c;
      const unsigned short* p1 = zb + (size_t)s1 * D + c;
      const unsigned short* p2 = zb + (size_t)s2 * D + c;
      const unsigned short* p3 = zb + (size_t)s3 * D + c;
      bf16x8 a0 = *(const bf16x8*)(p0), a1 = *(const bf16x8*)(p0 + 8);
      bf16x8 b0 = *(const bf16x8*)(p1), b1 = *(const bf16x8*)(p1 + 8);
      bf16x8 c0 = *(const bf16x8*)(p2), c1 = *(const bf16x8*)(p2 + 8);
      bf16x8 d0 = *(const bf16x8*)(p3), d1 = *(const bf16x8*)(p3 + 8);
#pragma unroll
      for (int j = 0; j < 8; ++j) {
        acc[j]     += (bf2f((unsigned short)a0[j]) + bf2f((unsigned short)b0[j]))
                    + (bf2f((unsigned short)c0[j]) + bf2f((unsigned short)d0[j]));
        acc[j + 8] += (bf2f((unsigned short)a1[j]) + bf2f((unsigned short)b1[j]))
                    + (bf2f((unsigned short)c1[j]) + bf2f((unsigned short)d1[j]));
      }
    }
    if (e + 2 <= e1) {
      int s0 = csr_src[e + 0];
      int s1 = csr_src[e + 1];
      const unsigned short* p0 = zb + (size_t)s0 * D + c;
      const unsigned short* p1 = zb + (size_t)s1 * D + c;
      bf16x8 a0 = *(const bf16x8*)(p0), a1 = *(const bf16x8*)(p0 + 8);
      bf16x8 b0 = *(const bf16x8*)(p1), b1 = *(const bf16x8*)(p1 + 8);
#pragma unroll
      for (int j = 0; j < 8; ++j) {
        acc[j]     += bf2f((unsigned short)a0[j]) + bf2f((unsigned short)b0[j]);
        acc[j + 8] += bf2f((unsigned short)a1[j]) + bf2f((unsigned short)b1[j]);
      }
      e += 2;
    }
    if (e < e1) {
      int s0 = csr_src[e];
      const unsigned short* p0 = zb + (size_t)s0 * D + c;
      bf16x8 a0 = *(const bf16x8*)(p0), a1 = *(const bf16x8*)(p0 + 8);
#pragma unroll
      for (int j = 0; j < 8; ++j) {
        acc[j]     += bf2f((unsigned short)a0[j]);
        acc[j + 8] += bf2f((unsigned short)a1[j]);
      }
    }
  } else {
    for (; e + 2 <= e1; e += 2) {
      int s0 = csr_src[e + 0];
      int s1 = csr_src[e + 1];
      const float* p0 = zf + (size_t)s0 * D + c;
      const float* p1 = zf + (size_t)s1 * D + c;
      float4 u0 = *(const float4*)(p0);
      float4 u1 = *(const float4*)(p0 + 4);
      float4 u2 = *(const float4*)(p0 + 8);
      float4 u3 = *(const float4*)(p0 + 12);
      float4 w0 = *(const float4*)(p1);
      float4 w1 = *(const float4*)(p1 + 4);
      float4 w2 = *(const float4*)(p1 + 8);
      float4 w3 = *(const float4*)(p1 + 12);
      acc[0]  += u0.x + w0.x; acc[1]  += u0.y + w0.y;
      acc[2]  += u0.z + w0.z; acc[3]  += u0.w + w0.w;
      acc[4]  += u1.x + w1.x; acc[5]  += u1.y + w1.y;
      acc[6]  += u1.z + w1.z; acc[7]  += u1.w + w1.w;
      acc[8]  += u2.x + w2.x; acc[9]  += u2.y + w2.y;
      acc[10] += u2.z + w2.z; acc[11] += u2.w + w2.w;
      acc[12] += u3.x + w3.x; acc[13] += u3.y + w3.y;
      acc[14] += u3.z + w3.z; acc[15] += u3.w + w3.w;
    }
    if (e < e1) {
      int s0 = csr_src[e];
      const float* p0 = zf + (size_t)s0 * D + c;
      float4 u0 = *(const float4*)(p0);
      float4 u1 = *(const float4*)(p0 + 4);
      float4 u2 = *(const float4*)(p0 + 8);
      float4 u3 = *(const float4*)(p0 + 12);
      acc[0]  += u0.x; acc[1]  += u0.y; acc[2]  += u0.z; acc[3]  += u0.w;
      acc[4]  += u1.x; acc[5]  += u1.y; acc[6]  += u1.z; acc[7]  += u1.w;
      acc[8]  += u2.x; acc[9]  += u2.y; acc[10] += u2.z; acc[11] += u2.w;
      acc[12] += u3.x; acc[13] += u3.y; acc[14] += u3.z; acc[15] += u3.w;
    }
  }

  bf16x8 o0, o1;
#pragma unroll
  for (int j = 0; j < 8; ++j) {
    o0[j] = (short)f2bf(acc[j]);
    o1[j] = (short)f2bf(acc[j + 8]);
  }
  unsigned short* q = agg + (size_t)node * D + c;
  *(bf16x8*)(q)     = o0;
  *(bf16x8*)(q + 8) = o1;
}

// ---------------- fused per-layer MLP: z = ReLU(ReLU(A@W1+b1)@W2+b2) -------
// R7 restructure: weights loaded ONCE per block (W1 -> registers, W2 -> LDS),
// 2 adjacent 128-row tiles per block (grid 391), tile-1 A prefetched while
// tile-0 GEMM2 runs, 16-row halves (LDS fits: w2s 34KB + hs 17KB = 52KB),
// warp-private hs with no barriers in the tile loop, LDS-staged coalesced
// row stores (4 x 256B contiguous segments per instruction).
// R3/R4 evidence: the old per-fc weight reloads were 16 serial ~300cy L2
// rounds per warp per tile -- this removes ALL of them.

template<bool LAST>
__global__ __launch_bounds__(256, 2) void gemm_fused(const unsigned short* __restrict__ A,
    const unsigned short* __restrict__ Wt1, const float* __restrict__ b1v,
    const unsigned short* __restrict__ Wt2, const float* __restrict__ b2v,
    unsigned short* __restrict__ Zb, float* __restrict__ Zf, int M, int nt) {
  __shared__ unsigned short w2s[128][136];
  __shared__ unsigned short hs[4][16][136];
  int tid  = threadIdx.x;
  int lane = tid & 63;
  int wid  = tid >> 6;
  int c16  = lane & 15;
  int kq   = lane >> 4;
  int koff = kq * 8;

  // stage W2 -> LDS (coalesced 16B chunks; 2048 chunks / 256 threads = 8 ea)
#pragma unroll
  for (int i = 0; i < 8; ++i) {
    int chunk = i * 256 + tid;
    int row = chunk >> 4, k16 = chunk & 15;
    *(bf16x8*)&w2s[row][k16 * 8] = *(const bf16x8*)(Wt2 + (size_t)row * D + k16 * 8);
  }

  // hoist W1 fragments + both biases (once per block)
  bf16x8 bf1[8][4];
  float  bb1[8], bb2[8];
#pragma unroll
  for (int fc = 0; fc < 8; ++fc) {
    int col = fc * 16 + c16;
    bb1[fc] = b1v[col];
    bb2[fc] = b2v[col];
#pragma unroll
    for (int kk = 0; kk < 4; ++kk)
      bf1[fc][kk] = *(const bf16x8*)(Wt1 + (size_t)col * D + kk * 32 + koff);
  }

  int tile0 = blockIdx.x * 2;
  int tile1 = tile0 + 1;

  auto LOADA = [&](bf16x8 (&dst)[2][4], int tile) {
#pragma unroll
    for (int h = 0; h < 2; ++h) {
      int row = tile * 128 + wid * 32 + h * 16 + c16;
      row = row < M ? row : M - 1;
#pragma unroll
      for (int kk = 0; kk < 4; ++kk)
        dst[h][kk] = *(const bf16x8*)(A + (size_t)row * D + kk * 32 + koff);
    }
  };

  bf16x8 aA[2][4], aB[2][4];
  LOADA(aA, tile0);
  __syncthreads();   // w2s ready

  auto DO_HALF = [&](const bf16x8 (&a)[4], int rb) {
    // GEMM1 half -> hs (warp-private; in-wave DS ordering, no barrier)
#pragma unroll
    for (int fc = 0; fc < 8; ++fc) {
      f32x4 acc = {0.f, 0.f, 0.f, 0.f};
#pragma unroll
      for (int kk = 0; kk < 4; ++kk)
        acc = __builtin_amdgcn_mfma_f32_16x16x32_bf16(a[kk], bf1[fc][kk], acc, 0, 0, 0);
      int col = fc * 16 + c16;
#pragma unroll
      for (int r = 0; r < 4; ++r)
        hs[wid][kq * 4 + r][col] = f2bf(fmaxf(acc[r] + bb1[fc], 0.f));
    }
    bf16x8 a2[4];
#pragma unroll
    for (int kk = 0; kk < 4; ++kk)
      a2[kk] = *(const bf16x8*)&hs[wid][c16][kk * 32 + koff];
    // GEMM2 half (B from LDS)
#pragma unroll
    for (int fc = 0; fc < 8; ++fc) {
      f32x4 acc = {0.f, 0.f, 0.f, 0.f};
      int col = fc * 16 + c16;
#pragma unroll
      for (int kk = 0; kk < 4; ++kk) {
        bf16x8 b = *(const bf16x8*)&w2s[col][kk * 32 + koff];
        acc = __builtin_amdgcn_mfma_f32_16x16x32_bf16(a2[kk], b, acc, 0, 0, 0);
      }
      if constexpr (LAST) {
#pragma unroll
        for (int r = 0; r < 4; ++r) {
          int row = rb + kq * 4 + r;
          if (row < M) Zf[(size_t)row * D + col] = fmaxf(acc[r] + bb2[fc], 0.f);
        }
      } else {
#pragma unroll
        for (int r = 0; r < 4; ++r)
          hs[wid][kq * 4 + r][col] = f2bf(fmaxf(acc[r] + bb2[fc], 0.f));
      }
    }
    if constexpr (!LAST) {
      // coalesced row stores: per i, 4 rows x 256B contiguous segments
#pragma unroll
      for (int i = 0; i < 4; ++i) {
        int rl = i * 4 + kq;
        bf16x8 v = *(const bf16x8*)&hs[wid][rl][c16 * 8];
        int row = rb + rl;
        if (row < M)
          *(bf16x8*)(Zb + (size_t)row * D + c16 * 8) = v;
      }
    }
  };

  // tile 0
  DO_HALF(aA[0], tile0 * 128 + wid * 32);
  if (tile1 < nt) LOADA(aB, tile1);            // prefetch under tile0 work
  DO_HALF(aA[1], tile0 * 128 + wid * 32 + 16);
  // tile 1
  if (tile1 < nt) {
    DO_HALF(aB[0], tile1 * 128 + wid * 32);
    DO_HALF(aB[1], tile1 * 128 + wid * 32 + 16);
  }
}

// ---------------- pooling: sorted batch -> bounds + streaming mean ---------

__global__ __launch_bounds__(128) void pool_bounds(const int* __restrict__ batch,
                                                   int* __restrict__ start, int N) {
  int g = threadIdx.x;   // one block of 128
  int lo = 0, hi = N;
  while (lo < hi) {
    int mid = (lo + hi) >> 1;
    if (batch[mid] < g) lo = mid + 1; else hi = mid;
  }
  start[g] = lo;
  if (g == 0) start[NG] = N;
}

#define PCHUNKS 8
__global__ __launch_bounds__(128) void pool_mean(const float* __restrict__ z,
    const int* __restrict__ start, float* __restrict__ g) {
  int gid   = blockIdx.x >> 3;
  int chunk = blockIdx.x & (PCHUNKS - 1);
  int col = threadIdx.x;
  int s = start[gid], epos = start[gid + 1];
  int len = epos - s;
  if (len <= 0) return;
  int per = (len + PCHUNKS - 1) / PCHUNKS;
  int r0 = s + chunk * per;
  int r1 = min(r0 + per, epos);
  if (r0 >= r1) return;
  float a0 = 0.f, a1 = 0.f, a2 = 0.f, a3 = 0.f;
  int i = r0;
  for (; i + 4 <= r1; i += 4) {
    a0 += z[(size_t)(i + 0) * D + col];
    a1 += z[(size_t)(i + 1) * D + col];
    a2 += z[(size_t)(i + 2) * D + col];
    a3 += z[(size_t)(i + 3) * D + col];
  }
  for (; i < r1; ++i) a0 += z[(size_t)i * D + col];
  atomicAdd(g + (size_t)gid * D + col, (a0 + a1) + (a2 + a3));
}

__global__ void pool_div(float* __restrict__ g, const int* __restrict__ start) {
  int t = blockIdx.x * 256 + threadIdx.x;
  if (t >= NG * D) return;
  int gid = t >> 7;
  int cnt = start[gid + 1] - start[gid];
  g[t] = g[t] / fmaxf((float)cnt, 1.f);
}

extern "C" void kernel_launch(void* const* d_in, const int* in_sizes, int n_in,
                              void* d_out, int out_size, void* d_ws, size_t ws_size,
                              hipStream_t stream) {
  const float* x     = (const float*)d_in[0];
  const int*   ei    = (const int*)d_in[1];
  const int*   batch = (const int*)d_in[2];
  const float* W1    = (const float*)d_in[3];
  const float* b1    = (const float*)d_in[4];
  const float* W2    = (const float*)d_in[5];
  const float* b2    = (const float*)d_in[6];

  const int N = in_sizes[0] / D;       // 100000
  const int E = in_sizes[1] / 2;       // 640000
  const int* src = ei;
  const int* dst = ei + E;

  float* zout = (float*)d_out;
  float* g    = zout + (size_t)N * D;

  // workspace layout
  char* w = (char*)d_ws;
  unsigned short* agg     = (unsigned short*)w;    w += (size_t)N * D * 2;
  unsigned short* zb      = (unsigned short*)w;    w += (size_t)N * D * 2;
  unsigned short* Wt1     = (unsigned short*)w;    w += 3 * 16384 * 2;
  unsigned short* Wt2     = (unsigned short*)w;    w += 3 * 16384 * 2;
  int*            start   = (int*)w;               w += (NG + 4) * 4;
  int*            deg     = (int*)w;               w += (size_t)N * 4;
  int*            rowptr  = (int*)w;               w += (size_t)(N + 4) * 4;
  int*            pos     = (int*)w;               w += (size_t)N * 4;
  int*            bsum    = (int*)w;               w += 128 * 4;
  int*            csr_src = (int*)w;               w += (size_t)E * 4;

  const int nb = (N + 1023) / 1024;   // 98 <= 128

  // weight prep + deg/g zero (folded)
  int prep_threads = (3 * 128 * 128 > N) ? 3 * 128 * 128 : N;
  prep_w<<<(prep_threads + 255) / 256, 256, 0, stream>>>(W1, W2, Wt1, Wt2, deg, N, g);

  // graph boundaries (only needs batch; run early)
  pool_bounds<<<1, 128, 0, stream>>>(batch, start, N);

  // CSR build
  hist_deg<<<(E + 255) / 256, 256, 0, stream>>>(dst, deg, E);
  scan1<<<nb, 256, 0, stream>>>(deg, rowptr, bsum, N);
  scan2<<<1, 128, 0, stream>>>(bsum, nb);
  scan3<<<(N + 255) / 256, 256, 0, stream>>>(rowptr, pos, bsum, N, E);
  edge_scatter<<<(E + 255) / 256, 256, 0, stream>>>(src, dst, pos, csr_src, E);

  const int gather_blocks = (int)(((size_t)N * 8 + 255) / 256);   // 3125
  const int nt            = (N + 127) / 128;                      // 782 tiles
  const int gemm_blocks   = (nt + 1) / 2;                         // 391

  // layer 0 (input f32 x)
  gather_agg<false><<<gather_blocks, 256, 0, stream>>>(x, rowptr, csr_src, agg, N);
  gemm_fused<false><<<gemm_blocks, 256, 0, stream>>>(agg, Wt1, b1, Wt2, b2, zb, zout, N, nt);
  // layer 1
  gather_agg<true><<<gather_blocks, 256, 0, stream>>>(zb, rowptr, csr_src, agg, N);
  gemm_fused<false><<<gemm_blocks, 256, 0, stream>>>(agg, Wt1 + 16384, b1 + 128,
                                                     Wt2 + 16384, b2 + 128, zb, zout, N, nt);
  // layer 2 (writes f32 zout)
  gather_agg<true><<<gather_blocks, 256, 0, stream>>>(zb, rowptr, csr_src, agg, N);
  gemm_fused<true><<<gemm_blocks, 256, 0, stream>>>(agg, Wt1 + 32768, b1 + 256,
                                                    Wt2 + 32768, b2 + 256, zb, zout, N, nt);

  pool_mean<<<NG * PCHUNKS, 128, 0, stream>>>(zout, start, g);
  pool_div<<<(NG * D + 255) / 256, 256, 0, stream>>>(g, start);
}

// Round 8
// 279.429 us; speedup vs baseline: 1.7505x; 1.0357x over previous
//
#include <hip/hip_runtime.h>
#include <hip/hip_bf16.h>

#define D 128
#define NG 128

typedef __attribute__((ext_vector_type(8))) short bf16x8;
typedef __attribute__((ext_vector_type(4))) float f32x4;

__device__ inline unsigned short f2bf(float f) {
  union { float f; unsigned u; } c; c.f = f;
  unsigned u = c.u;
  return (unsigned short)((u + 0x7FFFu + ((u >> 16) & 1u)) >> 16);  // RNE
}
__device__ inline float bf2f(unsigned short b) {
  union { unsigned u; float f; } c; c.u = ((unsigned)b) << 16;
  return c.f;
}

// Transpose + bf16-convert weights: Wt[l][n][k] = bf16(W[l][k][n]).
// Also zeroes deg[]/g[] and computes pool graph bounds (folded launches).
__global__ void prep_w(const float* __restrict__ W1, const float* __restrict__ W2,
                       unsigned short* __restrict__ Wt1, unsigned short* __restrict__ Wt2,
                       int* __restrict__ deg, int N, float* __restrict__ g,
                       const int* __restrict__ batch, int* __restrict__ start) {
  int t = blockIdx.x * 256 + threadIdx.x;
  if (t < N) deg[t] = 0;
  if (t < NG * D) g[t] = 0.f;
  if (t < NG) {          // graph boundary binary search (batch is sorted)
    int lo = 0, hi = N;
    while (lo < hi) {
      int mid = (lo + hi) >> 1;
      if (batch[mid] < t) lo = mid + 1; else hi = mid;
    }
    start[t] = lo;
    if (t == 0) start[NG] = N;
  }
  if (t >= 3 * 128 * 128) return;
  int l = t >> 14, k = (t >> 7) & 127, n = t & 127;
  int o = (l << 14) + (n << 7) + k;
  Wt1[o] = f2bf(W1[t]);
  Wt2[o] = f2bf(W2[t]);
}

// ---------------- CSR build ------------------------------------------------

__global__ void hist_deg(const int* __restrict__ dst, int* __restrict__ deg, int E) {
  int e = blockIdx.x * 256 + threadIdx.x;
  if (e < E) atomicAdd(deg + dst[e], 1);
}

__global__ __launch_bounds__(256) void scan1(const int* __restrict__ deg,
    int* __restrict__ rowptr, int* __restrict__ bsum, int n) {
  __shared__ int sh[256];
  int tid = threadIdx.x;
  int idx = blockIdx.x * 1024 + tid * 4;
  int v[4], tsum = 0;
#pragma unroll
  for (int j = 0; j < 4; ++j) { v[j] = (idx + j < n) ? deg[idx + j] : 0; tsum += v[j]; }
  sh[tid] = tsum;
  __syncthreads();
  for (int off = 1; off < 256; off <<= 1) {
    int x = (tid >= off) ? sh[tid - off] : 0;
    __syncthreads();
    sh[tid] += x;
    __syncthreads();
  }
  if (tid == 255) bsum[blockIdx.x] = sh[255];
  int run = sh[tid] - tsum;
#pragma unroll
  for (int j = 0; j < 4; ++j) { if (idx + j < n) rowptr[idx + j] = run; run += v[j]; }
}

// single 128-thread block scan of per-block sums (nb <= 128)
__global__ __launch_bounds__(128) void scan2(int* __restrict__ bsum, int nb) {
  __shared__ int sh[128];
  int tid = threadIdx.x;
  int v = (tid < nb) ? bsum[tid] : 0;
  sh[tid] = v;
  __syncthreads();
  for (int off = 1; off < 128; off <<= 1) {
    int x = (tid >= off) ? sh[tid - off] : 0;
    __syncthreads();
    sh[tid] += x;
    __syncthreads();
  }
  if (tid < nb) bsum[tid] = sh[tid] - v;
}

__global__ void scan3(int* __restrict__ rowptr, int* __restrict__ pos,
                      const int* __restrict__ bsum, int n, int E) {
  int t = blockIdx.x * 256 + threadIdx.x;
  if (t < n) {
    int v = rowptr[t] + bsum[t >> 10];
    rowptr[t] = v;
    pos[t] = v;
  }
  if (t == 0) rowptr[n] = E;
}

__global__ void edge_scatter(const int* __restrict__ src, const int* __restrict__ dst,
                             int* __restrict__ pos, int* __restrict__ csr_src, int E) {
  int e = blockIdx.x * 256 + threadIdx.x;
  if (e >= E) return;
  int idx = atomicAdd(pos + dst[e], 1);
  csr_src[idx] = src[e];
}

// ---------------- gather aggregation: agg[i] = z[i] + sum neighbors --------
// ROOFLINED for this pattern (6 rounds of evidence): ~57us at ~3.6 TB/s
// L2-miss BW, invariant to ILP depth, lanes/node, occupancy and payload
// width. Uniform-random graph -> no L2 locality exists (per-XCD 4MB <<
// 25.6MB working set); random 256B granules stream from L3 at ~3.6 TB/s.

template<bool IN_BF16>
__global__ __launch_bounds__(256) void gather_agg(const void* __restrict__ zin,
    const int* __restrict__ rowptr, const int* __restrict__ csr_src,
    unsigned short* __restrict__ agg, int N) {
  int t = blockIdx.x * 256 + threadIdx.x;
  int node = t >> 3;
  if (node >= N) return;
  int c = (t & 7) * 16;    // 16 elements per lane: 32B bf16 / 64B f32
  const float* zf = (const float*)zin;
  const unsigned short* zb = (const unsigned short*)zin;

  float acc[16];

  // self term
  if constexpr (IN_BF16) {
    const unsigned short* p = zb + (size_t)node * D + c;
    bf16x8 v0 = *(const bf16x8*)(p);
    bf16x8 v1 = *(const bf16x8*)(p + 8);
#pragma unroll
    for (int j = 0; j < 8; ++j) {
      acc[j]     = bf2f((unsigned short)v0[j]);
      acc[j + 8] = bf2f((unsigned short)v1[j]);
    }
  } else {
    const float* p = zf + (size_t)node * D + c;
    float4 v0 = *(const float4*)(p);
    float4 v1 = *(const float4*)(p + 4);
    float4 v2 = *(const float4*)(p + 8);
    float4 v3 = *(const float4*)(p + 12);
    acc[0]  = v0.x; acc[1]  = v0.y; acc[2]  = v0.z; acc[3]  = v0.w;
    acc[4]  = v1.x; acc[5]  = v1.y; acc[6]  = v1.z; acc[7]  = v1.w;
    acc[8]  = v2.x; acc[9]  = v2.y; acc[10] = v2.z; acc[11] = v2.w;
    acc[12] = v3.x; acc[13] = v3.y; acc[14] = v3.z; acc[15] = v3.w;
  }

  int e  = rowptr[node];
  int e1 = rowptr[node + 1];

  if constexpr (IN_BF16) {
    for (; e + 4 <= e1; e += 4) {
      int s0 = csr_src[e + 0];
      int s1 = csr_src[e + 1];
      int s2 = csr_src[e + 2];
      int s3 = csr_src[e + 3];
      const unsigned short* p0 = zb + (size_t)s0 * D + c;
      const unsigned short* p1 = zb + (size_t)s1 * D + c;
      const unsigned short* p2 = zb + (size_t)s2 * D + c;
      const unsigned short* p3 = zb + (size_t)s3 * D + c;
      bf16x8 a0 = *(const bf16x8*)(p0), a1 = *(const bf16x8*)(p0 + 8);
      bf16x8 b0 = *(const bf16x8*)(p1), b1 = *(const bf16x8*)(p1 + 8);
      bf16x8 c0 = *(const bf16x8*)(p2), c1 = *(const bf16x8*)(p2 + 8);
      bf16x8 d0 = *(const bf16x8*)(p3), d1 = *(const bf16x8*)(p3 + 8);
#pragma unroll
      for (int j = 0; j < 8; ++j) {
        acc[j]     += (bf2f((unsigned short)a0[j]) + bf2f((unsigned short)b0[j]))
                    + (bf2f((unsigned short)c0[j]) + bf2f((unsigned short)d0[j]));
        acc[j + 8] += (bf2f((unsigned short)a1[j]) + bf2f((unsigned short)b1[j]))
                    + (bf2f((unsigned short)c1[j]) + bf2f((unsigned short)d1[j]));
      }
    }
    if (e + 2 <= e1) {
      int s0 = csr_src[e + 0];
      int s1 = csr_src[e + 1];
      const unsigned short* p0 = zb + (size_t)s0 * D + c;
      const unsigned short* p1 = zb + (size_t)s1 * D + c;
      bf16x8 a0 = *(const bf16x8*)(p0), a1 = *(const bf16x8*)(p0 + 8);
      bf16x8 b0 = *(const bf16x8*)(p1), b1 = *(const bf16x8*)(p1 + 8);
#pragma unroll
      for (int j = 0; j < 8; ++j) {
        acc[j]     += bf2f((unsigned short)a0[j]) + bf2f((unsigned short)b0[j]);
        acc[j + 8] += bf2f((unsigned short)a1[j]) + bf2f((unsigned short)b1[j]);
      }
      e += 2;
    }
    if (e < e1) {
      int s0 = csr_src[e];
      const unsigned short* p0 = zb + (size_t)s0 * D + c;
      bf16x8 a0 = *(const bf16x8*)(p0), a1 = *(const bf16x8*)(p0 + 8);
#pragma unroll
      for (int j = 0; j < 8; ++j) {
        acc[j]     += bf2f((unsigned short)a0[j]);
        acc[j + 8] += bf2f((unsigned short)a1[j]);
      }
    }
  } else {
    for (; e + 2 <= e1; e += 2) {
      int s0 = csr_src[e + 0];
      int s1 = csr_src[e + 1];
      const float* p0 = zf + (size_t)s0 * D + c;
      const float* p1 = zf + (size_t)s1 * D + c;
      float4 u0 = *(const float4*)(p0);
      float4 u1 = *(const float4*)(p0 + 4);
      float4 u2 = *(const float4*)(p0 + 8);
      float4 u3 = *(const float4*)(p0 + 12);
      float4 w0 = *(const float4*)(p1);
      float4 w1 = *(const float4*)(p1 + 4);
      float4 w2 = *(const float4*)(p1 + 8);
      float4 w3 = *(const float4*)(p1 + 12);
      acc[0]  += u0.x + w0.x; acc[1]  += u0.y + w0.y;
      acc[2]  += u0.z + w0.z; acc[3]  += u0.w + w0.w;
      acc[4]  += u1.x + w1.x; acc[5]  += u1.y + w1.y;
      acc[6]  += u1.z + w1.z; acc[7]  += u1.w + w1.w;
      acc[8]  += u2.x + w2.x; acc[9]  += u2.y + w2.y;
      acc[10] += u2.z + w2.z; acc[11] += u2.w + w2.w;
      acc[12] += u3.x + w3.x; acc[13] += u3.y + w3.y;
      acc[14] += u3.z + w3.z; acc[15] += u3.w + w3.w;
    }
    if (e < e1) {
      int s0 = csr_src[e];
      const float* p0 = zf + (size_t)s0 * D + c;
      float4 u0 = *(const float4*)(p0);
      float4 u1 = *(const float4*)(p0 + 4);
      float4 u2 = *(const float4*)(p0 + 8);
      float4 u3 = *(const float4*)(p0 + 12);
      acc[0]  += u0.x; acc[1]  += u0.y; acc[2]  += u0.z; acc[3]  += u0.w;
      acc[4]  += u1.x; acc[5]  += u1.y; acc[6]  += u1.z; acc[7]  += u1.w;
      acc[8]  += u2.x; acc[9]  += u2.y; acc[10] += u2.z; acc[11] += u2.w;
      acc[12] += u3.x; acc[13] += u3.y; acc[14] += u3.z; acc[15] += u3.w;
    }
  }

  bf16x8 o0, o1;
#pragma unroll
  for (int j = 0; j < 8; ++j) {
    o0[j] = (short)f2bf(acc[j]);
    o1[j] = (short)f2bf(acc[j + 8]);
  }
  unsigned short* q = agg + (size_t)node * D + c;
  *(bf16x8*)(q)     = o0;
  *(bf16x8*)(q + 8) = o1;
}

// ---------------- fused per-layer MLP: z = ReLU(ReLU(A@W1+b1)@W2+b2) -------
// R8: weights once per block (W1->reg, W2->LDS), 2 tiles of 128 rows, BOTH
// tiles' A-fragments loaded up front (16 loads/lane in flight under the
// weight-stage latency), full 32-row tiles: 2 serial LDS chains per tile
// (vs R7's 4) and 2-row-fragment B-reuse (each B frag feeds 2 MFMAs).
// hs warp-private -> no barriers after the w2s one. Non-LAST z staged in hs
// then stored as 256B row segments (avoids 32B-segment write amplification).
// LAST f32 col-stores are 64B-aligned segments (no amplification) -> direct.

template<bool LAST>
__global__ __launch_bounds__(256, 2) void gemm_fused(const unsigned short* __restrict__ A,
    const unsigned short* __restrict__ Wt1, const float* __restrict__ b1v,
    const unsigned short* __restrict__ Wt2, const float* __restrict__ b2v,
    unsigned short* __restrict__ Zb, float* __restrict__ Zf, int M, int nt) {
  __shared__ unsigned short w2s[128][136];
  __shared__ unsigned short hs[4][32][136];
  int tid  = threadIdx.x;
  int lane = tid & 63;
  int wid  = tid >> 6;
  int c16  = lane & 15;
  int kq   = lane >> 4;
  int koff = kq * 8;

  int tile0 = blockIdx.x * 2;
  int tile1 = tile0 + 1;

  // issue BOTH tiles' A-loads first (latency hidden under weight staging)
  bf16x8 aA[2][4], aB[2][4];
#pragma unroll
  for (int h = 0; h < 2; ++h) {
    int rowA = tile0 * 128 + wid * 32 + h * 16 + c16;
    rowA = rowA < M ? rowA : M - 1;
    int rowB = tile1 * 128 + wid * 32 + h * 16 + c16;
    rowB = rowB < M ? rowB : M - 1;
#pragma unroll
    for (int kk = 0; kk < 4; ++kk) {
      aA[h][kk] = *(const bf16x8*)(A + (size_t)rowA * D + kk * 32 + koff);
      aB[h][kk] = *(const bf16x8*)(A + (size_t)rowB * D + kk * 32 + koff);
    }
  }

  // stage W2 -> LDS (coalesced 16B chunks; 2048 chunks / 256 threads = 8 ea)
#pragma unroll
  for (int i = 0; i < 8; ++i) {
    int chunk = i * 256 + tid;
    int row = chunk >> 4, k16 = chunk & 15;
    *(bf16x8*)&w2s[row][k16 * 8] = *(const bf16x8*)(Wt2 + (size_t)row * D + k16 * 8);
  }

  // hoist W1 fragments + both biases (once per block)
  bf16x8 bf1[8][4];
  float  bb1[8], bb2[8];
#pragma unroll
  for (int fc = 0; fc < 8; ++fc) {
    int col = fc * 16 + c16;
    bb1[fc] = b1v[col];
    bb2[fc] = b2v[col];
#pragma unroll
    for (int kk = 0; kk < 4; ++kk)
      bf1[fc][kk] = *(const bf16x8*)(Wt1 + (size_t)col * D + kk * 32 + koff);
  }

  __syncthreads();   // w2s ready

  auto TILE = [&](const bf16x8 (&a)[2][4], int tile) {
    int rb = tile * 128 + wid * 32;
    // GEMM1 (full 32-row warp tile) -> hs; warp-private, in-wave ordering
#pragma unroll
    for (int fc = 0; fc < 8; ++fc) {
      f32x4 acc0 = {0.f, 0.f, 0.f, 0.f};
      f32x4 acc1 = {0.f, 0.f, 0.f, 0.f};
#pragma unroll
      for (int kk = 0; kk < 4; ++kk) {
        acc0 = __builtin_amdgcn_mfma_f32_16x16x32_bf16(a[0][kk], bf1[fc][kk], acc0, 0, 0, 0);
        acc1 = __builtin_amdgcn_mfma_f32_16x16x32_bf16(a[1][kk], bf1[fc][kk], acc1, 0, 0, 0);
      }
      int col = fc * 16 + c16;
#pragma unroll
      for (int r = 0; r < 4; ++r) {
        hs[wid][kq * 4 + r][col]      = f2bf(fmaxf(acc0[r] + bb1[fc], 0.f));
        hs[wid][kq * 4 + r + 16][col] = f2bf(fmaxf(acc1[r] + bb1[fc], 0.f));
      }
    }
    bf16x8 a2[2][4];
#pragma unroll
    for (int fr = 0; fr < 2; ++fr)
#pragma unroll
      for (int kk = 0; kk < 4; ++kk)
        a2[fr][kk] = *(const bf16x8*)&hs[wid][fr * 16 + c16][kk * 32 + koff];
    // GEMM2 (B from LDS)
#pragma unroll
    for (int fc = 0; fc < 8; ++fc) {
      f32x4 acc0 = {0.f, 0.f, 0.f, 0.f};
      f32x4 acc1 = {0.f, 0.f, 0.f, 0.f};
      int col = fc * 16 + c16;
#pragma unroll
      for (int kk = 0; kk < 4; ++kk) {
        bf16x8 b = *(const bf16x8*)&w2s[col][kk * 32 + koff];
        acc0 = __builtin_amdgcn_mfma_f32_16x16x32_bf16(a2[0][kk], b, acc0, 0, 0, 0);
        acc1 = __builtin_amdgcn_mfma_f32_16x16x32_bf16(a2[1][kk], b, acc1, 0, 0, 0);
      }
      if constexpr (LAST) {
#pragma unroll
        for (int r = 0; r < 4; ++r) {
          int row0 = rb + kq * 4 + r;
          if (row0 < M) Zf[(size_t)row0 * D + col] = fmaxf(acc0[r] + bb2[fc], 0.f);
          int row1 = row0 + 16;
          if (row1 < M) Zf[(size_t)row1 * D + col] = fmaxf(acc1[r] + bb2[fc], 0.f);
        }
      } else {
        // a2 already in registers -> safe to overwrite hs
#pragma unroll
        for (int r = 0; r < 4; ++r) {
          hs[wid][kq * 4 + r][col]      = f2bf(fmaxf(acc0[r] + bb2[fc], 0.f));
          hs[wid][kq * 4 + r + 16][col] = f2bf(fmaxf(acc1[r] + bb2[fc], 0.f));
        }
      }
    }
    if constexpr (!LAST) {
      // staged coalesced stores: per i, 4 rows x 256B contiguous segments
#pragma unroll
      for (int i = 0; i < 8; ++i) {
        int rl = i * 4 + kq;
        bf16x8 v = *(const bf16x8*)&hs[wid][rl][c16 * 8];
        int row = rb + rl;
        if (row < M)
          *(bf16x8*)(Zb + (size_t)row * D + c16 * 8) = v;
      }
    }
  };

  TILE(aA, tile0);
  if (tile1 < nt) TILE(aB, tile1);
}

// ---------------- pooling: bounds (in prep_w) + streaming mean -------------

#define PCHUNKS 8
__global__ __launch_bounds__(128) void pool_mean(const float* __restrict__ z,
    const int* __restrict__ start, float* __restrict__ g) {
  int gid   = blockIdx.x >> 3;
  int chunk = blockIdx.x & (PCHUNKS - 1);
  int col = threadIdx.x;
  int s = start[gid], epos = start[gid + 1];
  int len = epos - s;
  if (len <= 0) return;
  int per = (len + PCHUNKS - 1) / PCHUNKS;
  int r0 = s + chunk * per;
  int r1 = min(r0 + per, epos);
  if (r0 >= r1) return;
  float a0 = 0.f, a1 = 0.f, a2 = 0.f, a3 = 0.f;
  int i = r0;
  for (; i + 4 <= r1; i += 4) {
    a0 += z[(size_t)(i + 0) * D + col];
    a1 += z[(size_t)(i + 1) * D + col];
    a2 += z[(size_t)(i + 2) * D + col];
    a3 += z[(size_t)(i + 3) * D + col];
  }
  for (; i < r1; ++i) a0 += z[(size_t)i * D + col];
  atomicAdd(g + (size_t)gid * D + col, (a0 + a1) + (a2 + a3));
}

__global__ void pool_div(float* __restrict__ g, const int* __restrict__ start) {
  int t = blockIdx.x * 256 + threadIdx.x;
  if (t >= NG * D) return;
  int gid = t >> 7;
  int cnt = start[gid + 1] - start[gid];
  g[t] = g[t] / fmaxf((float)cnt, 1.f);
}

extern "C" void kernel_launch(void* const* d_in, const int* in_sizes, int n_in,
                              void* d_out, int out_size, void* d_ws, size_t ws_size,
                              hipStream_t stream) {
  const float* x     = (const float*)d_in[0];
  const int*   ei    = (const int*)d_in[1];
  const int*   batch = (const int*)d_in[2];
  const float* W1    = (const float*)d_in[3];
  const float* b1    = (const float*)d_in[4];
  const float* W2    = (const float*)d_in[5];
  const float* b2    = (const float*)d_in[6];

  const int N = in_sizes[0] / D;       // 100000
  const int E = in_sizes[1] / 2;       // 640000
  const int* src = ei;
  const int* dst = ei + E;

  float* zout = (float*)d_out;
  float* g    = zout + (size_t)N * D;

  // workspace layout
  char* w = (char*)d_ws;
  unsigned short* agg     = (unsigned short*)w;    w += (size_t)N * D * 2;
  unsigned short* zb      = (unsigned short*)w;    w += (size_t)N * D * 2;
  unsigned short* Wt1     = (unsigned short*)w;    w += 3 * 16384 * 2;
  unsigned short* Wt2     = (unsigned short*)w;    w += 3 * 16384 * 2;
  int*            start   = (int*)w;               w += (NG + 4) * 4;
  int*            deg     = (int*)w;               w += (size_t)N * 4;
  int*            rowptr  = (int*)w;               w += (size_t)(N + 4) * 4;
  int*            pos     = (int*)w;               w += (size_t)N * 4;
  int*            bsum    = (int*)w;               w += 128 * 4;
  int*            csr_src = (int*)w;               w += (size_t)E * 4;

  const int nb = (N + 1023) / 1024;   // 98 <= 128

  // weight prep + deg/g zero + pool bounds (folded)
  int prep_threads = (3 * 128 * 128 > N) ? 3 * 128 * 128 : N;
  prep_w<<<(prep_threads + 255) / 256, 256, 0, stream>>>(W1, W2, Wt1, Wt2, deg, N, g,
                                                         batch, start);

  // CSR build
  hist_deg<<<(E + 255) / 256, 256, 0, stream>>>(dst, deg, E);
  scan1<<<nb, 256, 0, stream>>>(deg, rowptr, bsum, N);
  scan2<<<1, 128, 0, stream>>>(bsum, nb);
  scan3<<<(N + 255) / 256, 256, 0, stream>>>(rowptr, pos, bsum, N, E);
  edge_scatter<<<(E + 255) / 256, 256, 0, stream>>>(src, dst, pos, csr_src, E);

  const int gather_blocks = (int)(((size_t)N * 8 + 255) / 256);   // 3125
  const int nt            = (N + 127) / 128;                      // 782 tiles
  const int gemm_blocks   = (nt + 1) / 2;                         // 391

  // layer 0 (input f32 x)
  gather_agg<false><<<gather_blocks, 256, 0, stream>>>(x, rowptr, csr_src, agg, N);
  gemm_fused<false><<<gemm_blocks, 256, 0, stream>>>(agg, Wt1, b1, Wt2, b2, zb, zout, N, nt);
  // layer 1
  gather_agg<true><<<gather_blocks, 256, 0, stream>>>(zb, rowptr, csr_src, agg, N);
  gemm_fused<false><<<gemm_blocks, 256, 0, stream>>>(agg, Wt1 + 16384, b1 + 128,
                                                     Wt2 + 16384, b2 + 128, zb, zout, N, nt);
  // layer 2 (writes f32 zout)
  gather_agg<true><<<gather_blocks, 256, 0, stream>>>(zb, rowptr, csr_src, agg, N);
  gemm_fused<true><<<gemm_blocks, 256, 0, stream>>>(agg, Wt1 + 32768, b1 + 256,
                                                    Wt2 + 32768, b2 + 256, zb, zout, N, nt);

  pool_mean<<<NG * PCHUNKS, 128, 0, stream>>>(zout, start, g);
  pool_div<<<(NG * D + 255) / 256, 256, 0, stream>>>(g, start);
}